// Round 15
// baseline (86.173 us; speedup 1.0000x reference)
//
#include <hip/hip_runtime.h>
#include <hip/hip_bf16.h>
#include <string.h>

#define N 4096
#define D 512
#define NB 32            // N/128 regions; triangle regions = NB*(NB+1)/2 = 528
#define NBLK (NB*(NB+1)/2)
#define MARGIN 0.5f
#define FINF __builtin_huge_valf()
#define UINF 0x7F800000u

typedef __attribute__((ext_vector_type(4))) float f32x4;
typedef long fp8x8;      // 8 packed fp8-e4m3 (i64 MFMA operand)

__device__ inline float wave_sum(float v){
  #pragma unroll
  for (int off=32; off>0; off>>=1) v += __shfl_down(v, off, 64);
  return v;
}

// Pass 0: X (f32) -> fp8 e4m3 (2 MB panel), f32 row squared norms,
// init the atomic min/max arrays; block 0 also zeroes out[0].
__global__ __launch_bounds__(128) void prep_kernel(const float* __restrict__ X,
    unsigned char* __restrict__ Xq, float* __restrict__ sq,
    unsigned int* __restrict__ hp2u, unsigned int* __restrict__ nm2u,
    float* __restrict__ out){
  const int row = blockIdx.x;
  const int t = threadIdx.x;
  const float4 v = *(const float4*)(X + (size_t)row*D + t*4);
  int p0 = __builtin_amdgcn_cvt_pk_fp8_f32(v.x, v.y, 0, false);
  int p1 = __builtin_amdgcn_cvt_pk_fp8_f32(v.z, v.w, 0, false);
  unsigned int packed = (p0 & 0xFFFFu) | ((unsigned int)(p1 & 0xFFFFu) << 16);
  *(unsigned int*)(Xq + (size_t)row*D + t*4) = packed;
  float ss = v.x*v.x + v.y*v.y + v.z*v.z + v.w*v.w;
  ss = wave_sum(ss);
  __shared__ float red[2];
  if ((t & 63) == 0) red[t >> 6] = ss;
  __syncthreads();
  if (t == 0){
    sq[row] = red[0] + red[1];
    hp2u[row] = 0u;                 // max-accumulator (d^2 domain, >= 0)
    nm2u[row] = UINF;               // +inf: min-accumulator
    if (row == 0) out[0] = 0.0f;
  }
}

// Prewarm: stream the full 2 MB Xq panel (+ sq/lab) into EVERY XCD's L2 with
// max memory-level parallelism, so the gemm's K-loop doesn't demand-page cold
// lines behind its barriers. blockIdx&7 = XCD round-robin phase; blockIdx>>3
// selects an 8 KB slice; each phase collectively covers the whole panel.
__global__ __launch_bounds__(256) void warm_kernel(const float4* __restrict__ Xq4,
    const float* __restrict__ sq, const int* __restrict__ lab,
    float* __restrict__ sink){
  const int slice = blockIdx.x >> 3;                  // 0..255
  const float4* p = Xq4 + (size_t)slice * 512 + threadIdx.x;
  const float4 v = p[0];
  const float4 w = p[256];
  float s = v.x + v.y + v.z + v.w + w.x + w.y + w.z + w.w;
  s += sq[(blockIdx.x * 256 + threadIdx.x) & (N - 1)];
  s += (float)lab[(blockIdx.x * 64 + threadIdx.x) & (N - 1)];
  if (s == 1234567.891f) sink[0] = s;                 // defeat DCE, never taken
}

// Fused triangle GEMM (fp8 MFMA) + hardest-pos/neg reductions.
// R9/R14's best-measured structure: 128x128 tiles, BK=64 (8 slabs x
// 2 barriers), XOR-swizzled 16B LDS slots, no threadfence/ticket.
__global__ __launch_bounds__(256,2) void gemm_fused(const unsigned char* __restrict__ Xq,
    const float* __restrict__ sq, const int* __restrict__ lab,
    unsigned int* __restrict__ hp2u, unsigned int* __restrict__ nm2u){
  __shared__ __align__(16) unsigned char As[128*64];   // 8 KB
  __shared__ __align__(16) unsigned char Bs[128*64];   // 8 KB
  __shared__ float sqi[128];
  __shared__ float sqj[128];
  __shared__ int labi_s[128];
  __shared__ int labj_s[128];
  __shared__ unsigned int hpl[128], nml[128];   // region-row combine
  __shared__ unsigned int hpc[128], nmc[128];   // region-col combine

  // linear block -> region (bi, bj) with bi <= bj
  int rem = blockIdx.x, bi = 0;
  while (rem >= NB - bi){ rem -= NB - bi; bi++; }
  const int bj = bi + rem;
  const int row0 = bi * 128, col0 = bj * 128;

  const int tid = threadIdx.x;
  const int wave = tid >> 6, lane = tid & 63;
  const int wr = (wave >> 1) * 64, wc = (wave & 1) * 64;   // wave's 64x64 quadrant
  const int fr = lane & 15, q = lane >> 4;

  if (tid < 128) {
    sqi[tid] = sq[row0 + tid]; sqj[tid] = sq[col0 + tid];
    labi_s[tid] = lab[row0 + tid]; labj_s[tid] = lab[col0 + tid];
    hpl[tid] = 0u; nml[tid] = UINF; hpc[tid] = 0u; nmc[tid] = UINF;
  }

  // Staging: rows are 64 B = 4 x 16B slots. LDS slot s of row r holds global
  // chunk c = s ^ (r&3). Lane l: row = l>>2, slot = l&3 (dest = base+l*16),
  // fetches global chunk g = (l&3) ^ ((l>>2)&3).
  const int srow = lane >> 2;
  const int g16  = (lane & 3) ^ (srow & 3);

  f32x4 acc[4][4];
  #pragma unroll
  for (int a=0;a<4;a++)
    #pragma unroll
    for (int b=0;b<4;b++)
      acc[a][b] = (f32x4){0.f,0.f,0.f,0.f};

  for (int it = 0; it < D/64; ++it){
    const int k0 = it * 64;
    __syncthreads();   // previous iter's ds_reads done before overwrite
    #pragma unroll
    for (int c=0;c<2;c++){
      const int rg = wave*32 + c*16;   // wave-uniform 16-row group
      const unsigned char* ga = Xq + (size_t)(row0 + rg + srow)*D + k0 + g16*16;
      const unsigned char* gb = Xq + (size_t)(col0 + rg + srow)*D + k0 + g16*16;
      __builtin_amdgcn_global_load_lds((const __attribute__((address_space(1))) void*)ga,
          (__attribute__((address_space(3))) void*)(As + rg*64), 16, 0, 0);
      __builtin_amdgcn_global_load_lds((const __attribute__((address_space(1))) void*)gb,
          (__attribute__((address_space(3))) void*)(Bs + rg*64), 16, 0, 0);
    }
    __syncthreads();   // compiler drains vmcnt before barrier -> LDS valid

    // Fragment reads: A[m=fr][k = h*32 + q*8 + j]; 8B at swizzled slot.
    fp8x8 af[2][4], bfr[2][4];
    #pragma unroll
    for (int h=0;h<2;h++){
      const int c = h*2 + (q>>1);
      const int hb = (q&1)*8;
      #pragma unroll
      for (int a=0;a<4;a++){
        const int ra = a*16 + fr;
        af[h][a]  = *(const fp8x8*)(As + ra*64 + ((c ^ (ra&3))*16) + hb);
        bfr[h][a] = *(const fp8x8*)(Bs + ra*64 + ((c ^ (ra&3))*16) + hb);
      }
    }
    #pragma unroll
    for (int h=0;h<2;h++)
      #pragma unroll
      for (int a=0;a<4;a++)
        #pragma unroll
        for (int b=0;b<4;b++)
          acc[a][b] = __builtin_amdgcn_mfma_f32_16x16x32_fp8_fp8(af[h][a], bfr[h][b], acc[a][b], 0, 0, 0);
  }

  // Epilogue. C/D layout: col=lane&15, row=(lane>>4)*4+v (shape-determined).
  const int colq = lane & 15, g4 = lane >> 4, rowq = g4 * 4;
  int   labi_r[16]; float sqi_r[16];
  #pragma unroll
  for (int a=0;a<4;a++)
    #pragma unroll
    for (int v=0;v<4;v++){
      const int iloc = wr + a*16 + rowq + v;
      labi_r[a*4+v] = labi_s[iloc];
      sqi_r[a*4+v]  = sqi[iloc];
    }

  float pmax_r[16], nmin_r[16];
  #pragma unroll
  for (int k=0;k<16;k++){ pmax_r[k] = 0.f; nmin_r[k] = FINF; }
  float cpos[4], cmin[4];

  #pragma unroll
  for (int b=0;b<4;b++){
    const int jloc = wc + b*16 + colq;
    const float sj = sqj[jloc];
    const int lj = labj_s[jloc];
    float cp = 0.f, cn = FINF;
    #pragma unroll
    for (int a=0;a<4;a++)
      #pragma unroll
      for (int v=0;v<4;v++){
        const int k = a*4+v;
        const float d2 = fmaf(acc[a][b][v], -2.0f, sqi_r[k] + sj);
        const bool same = (labi_r[k] == lj);         // covers diag (i==j)
        const float sp = same ? d2 : 0.0f;           // positive candidate
        const float sn = same ? FINF : d2;           // negative candidate
        pmax_r[k] = fmaxf(pmax_r[k], sp);
        nmin_r[k] = fminf(nmin_r[k], sn);
        cp = fmaxf(cp, sp);
        cn = fminf(cn, sn);
      }
    cpos[b] = cp; cmin[b] = cn;
  }

  // Row-direction: xor-reduce across the 16 lanes sharing a row -> LDS atomic.
  #pragma unroll
  for (int k=0;k<16;k++){
    float p = pmax_r[k], n = nmin_r[k];
    #pragma unroll
    for (int m=1;m<16;m<<=1){
      p = fmaxf(p, __shfl_xor(p, m, 64));
      n = fminf(n, __shfl_xor(n, m, 64));
    }
    if (colq == 0){
      const int il = wr + (k>>2)*16 + rowq + (k&3);
      atomicMax(&hpl[il], __float_as_uint(p));                 // p >= 0
      atomicMin(&nml[il], __float_as_uint(fmaxf(n, 0.f)));     // clamp: monotone
    }
  }
  // Column-direction (symmetry): xor-reduce across the 4 lane-groups -> LDS atomic.
  #pragma unroll
  for (int b=0;b<4;b++){
    float p = cpos[b], n = cmin[b];
    p = fmaxf(p, __shfl_xor(p, 16, 64)); p = fmaxf(p, __shfl_xor(p, 32, 64));
    n = fminf(n, __shfl_xor(n, 16, 64)); n = fminf(n, __shfl_xor(n, 32, 64));
    if (g4 == 0){
      const int jl = wc + b*16 + colq;
      atomicMax(&hpc[jl], __float_as_uint(p));
      atomicMin(&nmc[jl], __float_as_uint(fmaxf(n, 0.f)));
    }
  }

  __syncthreads();
  // One global flush: threads 0-127 do region rows, 128-255 region cols.
  if (tid < 128){
    atomicMax(hp2u + row0 + tid, hpl[tid]);
    atomicMin(nm2u + row0 + tid, nml[tid]);
  } else {
    const int t2 = tid - 128;
    atomicMax(hp2u + col0 + t2, hpc[t2]);
    atomicMin(nm2u + col0 + t2, nmc[t2]);
  }
}

// Final: loss = mean(sqrt(hp2)) + mean(max(margin - sqrt(nm2), 0)).
// 16 blocks + one atomicAdd per block; out zeroed by prep.
__global__ __launch_bounds__(256) void final_reduce(const unsigned int* __restrict__ hp2u,
    const unsigned int* __restrict__ nm2u, float* __restrict__ out){
  const int i = blockIdx.x * 256 + threadIdx.x;
  const float hp2 = __uint_as_float(hp2u[i]);
  const float nm2 = __uint_as_float(nm2u[i]);
  float s = sqrtf(hp2 + 1e-12f) + fmaxf(MARGIN - sqrtf(nm2 + 1e-12f), 0.f);
  s = wave_sum(s);
  __shared__ float r[4];
  if ((threadIdx.x & 63) == 0) r[threadIdx.x >> 6] = s;
  __syncthreads();
  if (threadIdx.x == 0)
    atomicAdd(out, (r[0] + r[1] + r[2] + r[3]) * (1.0f / (float)N));
}

extern "C" void kernel_launch(void* const* d_in, const int* in_sizes, int n_in,
                              void* d_out, int out_size, void* d_ws, size_t ws_size,
                              hipStream_t stream) {
  (void)in_sizes; (void)n_in; (void)out_size; (void)ws_size;
  const float* X  = (const float*)d_in[0];
  const int* lab  = (const int*)d_in[1];
  float* out      = (float*)d_out;

  char* ws = (char*)d_ws;
  unsigned char* Xq     = (unsigned char*)ws;                  // 2 MB fp8
  float* sq             = (float*)(Xq + (size_t)N * D);        // 16 KB
  unsigned int* hp2u    = (unsigned int*)(sq + N);             // 16 KB
  unsigned int* nm2u    = hp2u + N;                            // 16 KB
  float* sink           = (float*)(nm2u + N);                  // 4 B (warm DCE guard)

  prep_kernel<<<N, 128, 0, stream>>>(X, Xq, sq, hp2u, nm2u, out);
  warm_kernel<<<2048, 256, 0, stream>>>((const float4*)Xq, sq, lab, sink);
  gemm_fused<<<NBLK, 256, 0, stream>>>(Xq, sq, lab, hp2u, nm2u);
  final_reduce<<<16, 256, 0, stream>>>(hp2u, nm2u, out);
}

// Round 16
// 82.139 us; speedup vs baseline: 1.0491x; 1.0491x over previous
//
#include <hip/hip_runtime.h>
#include <hip/hip_bf16.h>
#include <string.h>

#define N 4096
#define D 512
#define NB 32            // N/128 regions; triangle regions = NB*(NB+1)/2 = 528
#define NBLK (NB*(NB+1)/2)
#define MARGIN 0.5f
#define FINF __builtin_huge_valf()
#define UINF 0x7F800000u

typedef __attribute__((ext_vector_type(4))) float f32x4;
typedef long fp8x8;      // 8 packed fp8-e4m3 (i64 MFMA operand)

__device__ inline float wave_sum(float v){
  #pragma unroll
  for (int off=32; off>0; off>>=1) v += __shfl_down(v, off, 64);
  return v;
}

// Pass 0: X (f32) -> fp8 e4m3 (2 MB panel), f32 row squared norms,
// init the atomic min/max arrays; block 0 also zeroes out[0].
__global__ __launch_bounds__(128) void prep_kernel(const float* __restrict__ X,
    unsigned char* __restrict__ Xq, float* __restrict__ sq,
    unsigned int* __restrict__ hp2u, unsigned int* __restrict__ nm2u,
    float* __restrict__ out){
  const int row = blockIdx.x;
  const int t = threadIdx.x;
  const float4 v = *(const float4*)(X + (size_t)row*D + t*4);
  int p0 = __builtin_amdgcn_cvt_pk_fp8_f32(v.x, v.y, 0, false);
  int p1 = __builtin_amdgcn_cvt_pk_fp8_f32(v.z, v.w, 0, false);
  unsigned int packed = (p0 & 0xFFFFu) | ((unsigned int)(p1 & 0xFFFFu) << 16);
  *(unsigned int*)(Xq + (size_t)row*D + t*4) = packed;
  float ss = v.x*v.x + v.y*v.y + v.z*v.z + v.w*v.w;
  ss = wave_sum(ss);
  __shared__ float red[2];
  if ((t & 63) == 0) red[t >> 6] = ss;
  __syncthreads();
  if (t == 0){
    sq[row] = red[0] + red[1];
    hp2u[row] = 0u;                 // max-accumulator (d^2 domain, >= 0)
    nm2u[row] = UINF;               // +inf: min-accumulator
    if (row == 0) out[0] = 0.0f;
  }
}

// Fused triangle GEMM (fp8 MFMA) + hardest-pos/neg reductions.
// Best-measured structure (R9/R14): 128x128 tiles, BK=64 (8 slabs x
// 2 barriers), XOR-swizzled 16B LDS slots, no threadfence/ticket.
__global__ __launch_bounds__(256,2) void gemm_fused(const unsigned char* __restrict__ Xq,
    const float* __restrict__ sq, const int* __restrict__ lab,
    unsigned int* __restrict__ hp2u, unsigned int* __restrict__ nm2u){
  __shared__ __align__(16) unsigned char As[128*64];   // 8 KB
  __shared__ __align__(16) unsigned char Bs[128*64];   // 8 KB
  __shared__ float sqi[128];
  __shared__ float sqj[128];
  __shared__ int labi_s[128];
  __shared__ int labj_s[128];
  __shared__ unsigned int hpl[128], nml[128];   // region-row combine
  __shared__ unsigned int hpc[128], nmc[128];   // region-col combine

  // linear block -> region (bi, bj) with bi <= bj
  int rem = blockIdx.x, bi = 0;
  while (rem >= NB - bi){ rem -= NB - bi; bi++; }
  const int bj = bi + rem;
  const int row0 = bi * 128, col0 = bj * 128;

  const int tid = threadIdx.x;
  const int wave = tid >> 6, lane = tid & 63;
  const int wr = (wave >> 1) * 64, wc = (wave & 1) * 64;   // wave's 64x64 quadrant
  const int fr = lane & 15, q = lane >> 4;

  if (tid < 128) {
    sqi[tid] = sq[row0 + tid]; sqj[tid] = sq[col0 + tid];
    labi_s[tid] = lab[row0 + tid]; labj_s[tid] = lab[col0 + tid];
    hpl[tid] = 0u; nml[tid] = UINF; hpc[tid] = 0u; nmc[tid] = UINF;
  }

  // Staging: rows are 64 B = 4 x 16B slots. LDS slot s of row r holds global
  // chunk c = s ^ (r&3). Lane l: row = l>>2, slot = l&3 (dest = base+l*16),
  // fetches global chunk g = (l&3) ^ ((l>>2)&3).
  const int srow = lane >> 2;
  const int g16  = (lane & 3) ^ (srow & 3);

  f32x4 acc[4][4];
  #pragma unroll
  for (int a=0;a<4;a++)
    #pragma unroll
    for (int b=0;b<4;b++)
      acc[a][b] = (f32x4){0.f,0.f,0.f,0.f};

  for (int it = 0; it < D/64; ++it){
    const int k0 = it * 64;
    __syncthreads();   // previous iter's ds_reads done before overwrite
    #pragma unroll
    for (int c=0;c<2;c++){
      const int rg = wave*32 + c*16;   // wave-uniform 16-row group
      const unsigned char* ga = Xq + (size_t)(row0 + rg + srow)*D + k0 + g16*16;
      const unsigned char* gb = Xq + (size_t)(col0 + rg + srow)*D + k0 + g16*16;
      __builtin_amdgcn_global_load_lds((const __attribute__((address_space(1))) void*)ga,
          (__attribute__((address_space(3))) void*)(As + rg*64), 16, 0, 0);
      __builtin_amdgcn_global_load_lds((const __attribute__((address_space(1))) void*)gb,
          (__attribute__((address_space(3))) void*)(Bs + rg*64), 16, 0, 0);
    }
    __syncthreads();   // compiler drains vmcnt before barrier -> LDS valid

    // Fragment reads: A[m=fr][k = h*32 + q*8 + j]; 8B at swizzled slot.
    fp8x8 af[2][4], bfr[2][4];
    #pragma unroll
    for (int h=0;h<2;h++){
      const int c = h*2 + (q>>1);
      const int hb = (q&1)*8;
      #pragma unroll
      for (int a=0;a<4;a++){
        const int ra = a*16 + fr;
        af[h][a]  = *(const fp8x8*)(As + ra*64 + ((c ^ (ra&3))*16) + hb);
        bfr[h][a] = *(const fp8x8*)(Bs + ra*64 + ((c ^ (ra&3))*16) + hb);
      }
    }
    #pragma unroll
    for (int h=0;h<2;h++)
      #pragma unroll
      for (int a=0;a<4;a++)
        #pragma unroll
        for (int b=0;b<4;b++)
          acc[a][b] = __builtin_amdgcn_mfma_f32_16x16x32_fp8_fp8(af[h][a], bfr[h][b], acc[a][b], 0, 0, 0);
  }

  // Epilogue. C/D layout: col=lane&15, row=(lane>>4)*4+v (shape-determined).
  const int colq = lane & 15, g4 = lane >> 4, rowq = g4 * 4;
  int   labi_r[16]; float sqi_r[16];
  #pragma unroll
  for (int a=0;a<4;a++)
    #pragma unroll
    for (int v=0;v<4;v++){
      const int iloc = wr + a*16 + rowq + v;
      labi_r[a*4+v] = labi_s[iloc];
      sqi_r[a*4+v]  = sqi[iloc];
    }

  float pmax_r[16], nmin_r[16];
  #pragma unroll
  for (int k=0;k<16;k++){ pmax_r[k] = 0.f; nmin_r[k] = FINF; }
  float cpos[4], cmin[4];

  #pragma unroll
  for (int b=0;b<4;b++){
    const int jloc = wc + b*16 + colq;
    const float sj = sqj[jloc];
    const int lj = labj_s[jloc];
    float cp = 0.f, cn = FINF;
    #pragma unroll
    for (int a=0;a<4;a++)
      #pragma unroll
      for (int v=0;v<4;v++){
        const int k = a*4+v;
        const float d2 = fmaf(acc[a][b][v], -2.0f, sqi_r[k] + sj);
        const bool same = (labi_r[k] == lj);         // covers diag (i==j)
        const float sp = same ? d2 : 0.0f;           // positive candidate
        const float sn = same ? FINF : d2;           // negative candidate
        pmax_r[k] = fmaxf(pmax_r[k], sp);
        nmin_r[k] = fminf(nmin_r[k], sn);
        cp = fmaxf(cp, sp);
        cn = fminf(cn, sn);
      }
    cpos[b] = cp; cmin[b] = cn;
  }

  // Row-direction: xor-reduce across the 16 lanes sharing a row -> LDS atomic.
  #pragma unroll
  for (int k=0;k<16;k++){
    float p = pmax_r[k], n = nmin_r[k];
    #pragma unroll
    for (int m=1;m<16;m<<=1){
      p = fmaxf(p, __shfl_xor(p, m, 64));
      n = fminf(n, __shfl_xor(n, m, 64));
    }
    if (colq == 0){
      const int il = wr + (k>>2)*16 + rowq + (k&3);
      atomicMax(&hpl[il], __float_as_uint(p));                 // p >= 0
      atomicMin(&nml[il], __float_as_uint(fmaxf(n, 0.f)));     // clamp: monotone
    }
  }
  // Column-direction (symmetry): xor-reduce across the 4 lane-groups -> LDS atomic.
  #pragma unroll
  for (int b=0;b<4;b++){
    float p = cpos[b], n = cmin[b];
    p = fmaxf(p, __shfl_xor(p, 16, 64)); p = fmaxf(p, __shfl_xor(p, 32, 64));
    n = fminf(n, __shfl_xor(n, 16, 64)); n = fminf(n, __shfl_xor(n, 32, 64));
    if (g4 == 0){
      const int jl = wc + b*16 + colq;
      atomicMax(&hpc[jl], __float_as_uint(p));
      atomicMin(&nmc[jl], __float_as_uint(fmaxf(n, 0.f)));
    }
  }

  __syncthreads();
  // One global flush: threads 0-127 do region rows, 128-255 region cols.
  if (tid < 128){
    atomicMax(hp2u + row0 + tid, hpl[tid]);
    atomicMin(nm2u + row0 + tid, nml[tid]);
  } else {
    const int t2 = tid - 128;
    atomicMax(hp2u + col0 + t2, hpc[t2]);
    atomicMin(nm2u + col0 + t2, nmc[t2]);
  }
}

// Final: loss = mean(sqrt(hp2)) + mean(max(margin - sqrt(nm2), 0)).
// 16 blocks + one atomicAdd per block; out zeroed by prep.
__global__ __launch_bounds__(256) void final_reduce(const unsigned int* __restrict__ hp2u,
    const unsigned int* __restrict__ nm2u, float* __restrict__ out){
  const int i = blockIdx.x * 256 + threadIdx.x;
  const float hp2 = __uint_as_float(hp2u[i]);
  const float nm2 = __uint_as_float(nm2u[i]);
  float s = sqrtf(hp2 + 1e-12f) + fmaxf(MARGIN - sqrtf(nm2 + 1e-12f), 0.f);
  s = wave_sum(s);
  __shared__ float r[4];
  if ((threadIdx.x & 63) == 0) r[threadIdx.x >> 6] = s;
  __syncthreads();
  if (threadIdx.x == 0)
    atomicAdd(out, (r[0] + r[1] + r[2] + r[3]) * (1.0f / (float)N));
}

extern "C" void kernel_launch(void* const* d_in, const int* in_sizes, int n_in,
                              void* d_out, int out_size, void* d_ws, size_t ws_size,
                              hipStream_t stream) {
  (void)in_sizes; (void)n_in; (void)out_size; (void)ws_size;
  const float* X  = (const float*)d_in[0];
  const int* lab  = (const int*)d_in[1];
  float* out      = (float*)d_out;

  char* ws = (char*)d_ws;
  unsigned char* Xq     = (unsigned char*)ws;                  // 2 MB fp8
  float* sq             = (float*)(Xq + (size_t)N * D);        // 16 KB
  unsigned int* hp2u    = (unsigned int*)(sq + N);             // 16 KB
  unsigned int* nm2u    = hp2u + N;                            // 16 KB

  prep_kernel<<<N, 128, 0, stream>>>(X, Xq, sq, hp2u, nm2u, out);
  gemm_fused<<<NBLK, 256, 0, stream>>>(Xq, sq, lab, hp2u, nm2u);
  final_reduce<<<16, 256, 0, stream>>>(hp2u, nm2u, out);
}